// Round 1
// baseline (3306.237 us; speedup 1.0000x reference)
//
#include <hip/hip_runtime.h>
#include <math.h>

// Problem constants (B,S,D,H fixed by the reference)
constexpr int Bc = 2, Sc = 2048, Dc = 2048, Hc = 16, DHc = 128;
constexpr int Mc = Bc * Sc;   // 4096 rows of x
constexpr int N3 = 3 * Dc;    // 6144

// ---------------------------------------------------------------------------
// RoPE cos/sin tables: [S][64] each. inv_freq[j] = 10000^(-2j/128).
// ---------------------------------------------------------------------------
__global__ void rope_table_kernel(float* __restrict__ cosT, float* __restrict__ sinT) {
  int idx = blockIdx.x * 256 + threadIdx.x;   // S*64 = 131072 total
  int s = idx >> 6, j = idx & 63;
  float inv = powf(10000.0f, -(float)(2 * j) / 128.0f);
  float a = (float)s * inv;
  cosT[idx] = cosf(a);
  sinT[idx] = sinf(a);
}

// ---------------------------------------------------------------------------
// fp32 SGEMM, C[M,N] = A[M,2048] @ B[2048,N] + bias.
// 128x128 tile, BK=16, 256 threads, 8x8 micro-tile per thread.
// EPI=0: scatter into Q/K/V [B,H,S,DH] buffers (out0,out1,out2)
// EPI=1: plain row-major store to out0
// ---------------------------------------------------------------------------
template<int EPI>
__global__ __launch_bounds__(256)
void sgemm128(const float* __restrict__ A, const float* __restrict__ Bm,
              const float* __restrict__ bias, float* __restrict__ out0,
              float* __restrict__ out1, float* __restrict__ out2, int Ndim)
{
  constexpr int Kd = 2048;
  // pad 132: row stride 528B = 33*16 keeps float4 LDS accesses 16B-aligned
  __shared__ float As[16][132];   // transposed A tile: As[k][m]
  __shared__ float Bs[16][132];   // natural B tile:   Bs[k][n]
  const int t  = threadIdx.x;
  const int tx = t & 15, ty = t >> 4;
  const int m0 = blockIdx.y * 128;
  const int n0 = blockIdx.x * 128;

  float acc[8][8];
#pragma unroll
  for (int i = 0; i < 8; ++i)
#pragma unroll
    for (int j = 0; j < 8; ++j) acc[i][j] = 0.f;

  for (int k0 = 0; k0 < Kd; k0 += 16) {
#pragma unroll
    for (int r = 0; r < 2; ++r) {
      int id = t + 256 * r;
      // A tile: 128 rows x 16 k; transpose-store
      int arow = id >> 2, kc = (id & 3) << 2;
      float4 av = *(const float4*)&A[(size_t)(m0 + arow) * Kd + k0 + kc];
      As[kc + 0][arow] = av.x; As[kc + 1][arow] = av.y;
      As[kc + 2][arow] = av.z; As[kc + 3][arow] = av.w;
      // B tile: 16 k x 128 n; direct store
      int kr = id >> 5, nc = (id & 31) << 2;
      float4 bv = *(const float4*)&Bm[(size_t)(k0 + kr) * Ndim + n0 + nc];
      *(float4*)&Bs[kr][nc] = bv;
    }
    __syncthreads();
#pragma unroll
    for (int kk = 0; kk < 16; ++kk) {
      float a[8], b[8];
      *(float4*)&a[0] = *(const float4*)&As[kk][ty * 8];
      *(float4*)&a[4] = *(const float4*)&As[kk][ty * 8 + 4];
      // split columns tx*4 and 64+tx*4 -> 2-way bank aliasing only (free)
      *(float4*)&b[0] = *(const float4*)&Bs[kk][tx * 4];
      *(float4*)&b[4] = *(const float4*)&Bs[kk][64 + tx * 4];
#pragma unroll
      for (int i = 0; i < 8; ++i)
#pragma unroll
        for (int j = 0; j < 8; ++j) acc[i][j] = fmaf(a[i], b[j], acc[i][j]);
    }
    __syncthreads();
  }

  if (EPI == 0) {
    // Tile (128 cols, 128-aligned) lies inside one part (q/k/v) and one head.
    const int part = n0 >> 11;          // n0 / 2048
    const int h    = (n0 & 2047) >> 7;  // head within part
    float* outp = (part == 0) ? out0 : (part == 1 ? out1 : out2);
#pragma unroll
    for (int i = 0; i < 8; ++i) {
      int m = m0 + ty * 8 + i;
      int bb = m >> 11, sidx = m & 2047;  // tile never spans batch boundary
      float* dst = outp + ((size_t)(bb * Hc + h) * Sc + sidx) * DHc;
#pragma unroll
      for (int hf = 0; hf < 2; ++hf) {
        int c0 = hf * 64 + tx * 4;
        float4 v;
        v.x = acc[i][hf * 4 + 0] + bias[n0 + c0 + 0];
        v.y = acc[i][hf * 4 + 1] + bias[n0 + c0 + 1];
        v.z = acc[i][hf * 4 + 2] + bias[n0 + c0 + 2];
        v.w = acc[i][hf * 4 + 3] + bias[n0 + c0 + 3];
        *(float4*)&dst[c0] = v;
      }
    }
  } else {
#pragma unroll
    for (int i = 0; i < 8; ++i) {
      int m = m0 + ty * 8 + i;
      float* dst = out0 + (size_t)m * Ndim + n0;
#pragma unroll
      for (int hf = 0; hf < 2; ++hf) {
        int c0 = hf * 64 + tx * 4;
        float4 v;
        v.x = acc[i][hf * 4 + 0] + bias[n0 + c0 + 0];
        v.y = acc[i][hf * 4 + 1] + bias[n0 + c0 + 1];
        v.z = acc[i][hf * 4 + 2] + bias[n0 + c0 + 2];
        v.w = acc[i][hf * 4 + 3] + bias[n0 + c0 + 3];
        *(float4*)&dst[c0] = v;
      }
    }
  }
}

// ---------------------------------------------------------------------------
// In-place RoPE on Q and K ([B*H, S, 128]). One 128-thread block per row pair.
// rotate(u)[j] = u[2j+1] for j<64, -u[2(j-64)] for j>=64; cos/sin index j%64.
// ---------------------------------------------------------------------------
__global__ void rope_kernel(float* __restrict__ Q, float* __restrict__ K,
                            const float* __restrict__ cosT, const float* __restrict__ sinT) {
  const int row = blockIdx.x;        // 0 .. B*H*S-1
  const int j = threadIdx.x;         // 0..127
  const int s = row & (Sc - 1);
  __shared__ float uq[128], uk[128];
  const size_t off = (size_t)row * DHc + j;
  uq[j] = Q[off];
  uk[j] = K[off];
  __syncthreads();
  const float c  = cosT[s * 64 + (j & 63)];
  const float sn = sinT[s * 64 + (j & 63)];
  float rq, rk;
  if (j < 64) { rq = uq[2 * j + 1];        rk = uk[2 * j + 1]; }
  else        { rq = -uq[2 * (j - 64)];    rk = -uk[2 * (j - 64)]; }
  Q[off] = uq[j] * c + rq * sn;
  K[off] = uk[j] * c + rk * sn;
}

// ---------------------------------------------------------------------------
// Flash attention fp32. Block: 32 q-rows of one (b,h); iterate 32-key tiles.
// Q/K staged transposed ([d][row], pad 33 -> conflict-free ds_read2_b32).
// Online softmax (running m,l). O written in [B,S,H*DH] layout.
// Static LDS = 54KB -> 2 blocks/CU.
// ---------------------------------------------------------------------------
__global__ __launch_bounds__(256)
void attn_kernel(const float* __restrict__ Qg, const float* __restrict__ Kg,
                 const float* __restrict__ Vg, float* __restrict__ Og)
{
  __shared__ float Qs[128][33];
  __shared__ float Ks[128][33];
  __shared__ float Vs[32][132];
  __shared__ float Ps[32][36];
  const int t  = threadIdx.x;
  const int tx = t & 15, ty = t >> 4;   // tx: key dim, ty: query dim
  const int bid = blockIdx.x;
  const int qt = bid & 63;              // S/32 = 64 q-tiles
  const int bh = bid >> 6;              // 0..31
  const int q0 = qt * 32;
  const size_t base = (size_t)bh * Sc * DHc;

  // Stage Q tile transposed
#pragma unroll
  for (int r = 0; r < 4; ++r) {
    int id = t + 256 * r;
    int row = id >> 5, dc = (id & 31) << 2;
    float4 v = *(const float4*)&Qg[base + (size_t)(q0 + row) * DHc + dc];
    Qs[dc + 0][row] = v.x; Qs[dc + 1][row] = v.y;
    Qs[dc + 2][row] = v.z; Qs[dc + 3][row] = v.w;
  }

  float m_i[2] = {-3.0e38f, -3.0e38f};
  float l_i[2] = {0.f, 0.f};
  float acc[2][8];
#pragma unroll
  for (int i = 0; i < 2; ++i)
#pragma unroll
    for (int j = 0; j < 8; ++j) acc[i][j] = 0.f;

  for (int kt0 = 0; kt0 < Sc; kt0 += 32) {
#pragma unroll
    for (int r = 0; r < 4; ++r) {
      int id = t + 256 * r;
      int row = id >> 5, dc = (id & 31) << 2;
      float4 kv = *(const float4*)&Kg[base + (size_t)(kt0 + row) * DHc + dc];
      Ks[dc + 0][row] = kv.x; Ks[dc + 1][row] = kv.y;
      Ks[dc + 2][row] = kv.z; Ks[dc + 3][row] = kv.w;
      float4 vv = *(const float4*)&Vg[base + (size_t)(kt0 + row) * DHc + dc];
      *(float4*)&Vs[row][dc] = vv;
    }
    __syncthreads();  // covers Qs on first iteration too

    // S tile: rows ty*2+i, cols tx*2+j
    float sv[2][2] = {{0.f, 0.f}, {0.f, 0.f}};
#pragma unroll 4
    for (int d = 0; d < 128; ++d) {
      float a0 = Qs[d][ty * 2], a1 = Qs[d][ty * 2 + 1];
      float b0 = Ks[d][tx * 2], b1 = Ks[d][tx * 2 + 1];
      sv[0][0] = fmaf(a0, b0, sv[0][0]);
      sv[0][1] = fmaf(a0, b1, sv[0][1]);
      sv[1][0] = fmaf(a1, b0, sv[1][0]);
      sv[1][1] = fmaf(a1, b1, sv[1][1]);
    }
    const float scale = 0.08838834764831845f;  // 1/sqrt(128)
    float p[2][2];
#pragma unroll
    for (int i = 0; i < 2; ++i) {
      sv[i][0] *= scale; sv[i][1] *= scale;
      float mx = fmaxf(sv[i][0], sv[i][1]);
#pragma unroll
      for (int off = 1; off < 16; off <<= 1)
        mx = fmaxf(mx, __shfl_xor(mx, off));
      float mnew = fmaxf(m_i[i], mx);
      float sc = __expf(m_i[i] - mnew);
      p[i][0] = __expf(sv[i][0] - mnew);
      p[i][1] = __expf(sv[i][1] - mnew);
      float rs = p[i][0] + p[i][1];
#pragma unroll
      for (int off = 1; off < 16; off <<= 1)
        rs += __shfl_xor(rs, off);
      l_i[i] = l_i[i] * sc + rs;
      m_i[i] = mnew;
#pragma unroll
      for (int j = 0; j < 8; ++j) acc[i][j] *= sc;
      Ps[ty * 2 + i][tx * 2 + 0] = p[i][0];
      Ps[ty * 2 + i][tx * 2 + 1] = p[i][1];
    }
    __syncthreads();

    // O += P @ V ; cols tx*4.. and 64+tx*4..
#pragma unroll 4
    for (int kk = 0; kk < 32; ++kk) {
      float p0 = Ps[ty * 2 + 0][kk];
      float p1 = Ps[ty * 2 + 1][kk];
      float v0[4], v1[4];
      *(float4*)v0 = *(const float4*)&Vs[kk][tx * 4];
      *(float4*)v1 = *(const float4*)&Vs[kk][64 + tx * 4];
#pragma unroll
      for (int j = 0; j < 4; ++j) {
        acc[0][j]     = fmaf(p0, v0[j], acc[0][j]);
        acc[0][4 + j] = fmaf(p0, v1[j], acc[0][4 + j]);
        acc[1][j]     = fmaf(p1, v0[j], acc[1][j]);
        acc[1][4 + j] = fmaf(p1, v1[j], acc[1][4 + j]);
      }
    }
    __syncthreads();
  }

  const int b = bh >> 4, h = bh & 15;
#pragma unroll
  for (int i = 0; i < 2; ++i) {
    float inv_l = 1.0f / l_i[i];
    size_t rowoff = ((size_t)(b * Sc + q0 + ty * 2 + i)) * Dc + h * DHc;
#pragma unroll
    for (int hf = 0; hf < 2; ++hf) {
      int c0 = hf * 64 + tx * 4;
      float4 v;
      v.x = acc[i][hf * 4 + 0] * inv_l;
      v.y = acc[i][hf * 4 + 1] * inv_l;
      v.z = acc[i][hf * 4 + 2] * inv_l;
      v.w = acc[i][hf * 4 + 3] * inv_l;
      *(float4*)&Og[rowoff + c0] = v;
    }
  }
}

// ---------------------------------------------------------------------------
extern "C" void kernel_launch(void* const* d_in, const int* in_sizes, int n_in,
                              void* d_out, int out_size, void* d_ws, size_t ws_size,
                              hipStream_t stream) {
  const float* x    = (const float*)d_in[0];
  const float* Wqkv = (const float*)d_in[1];
  const float* bqkv = (const float*)d_in[2];
  const float* Wo   = (const float*)d_in[3];
  const float* bo   = (const float*)d_in[4];
  float* out = (float*)d_out;
  float* ws  = (float*)d_ws;

  // Workspace layout (floats): Q,K,V [B,H,S,DH]; O [B,S,D]; rope tables
  const size_t QKV = (size_t)Bc * Hc * Sc * DHc;   // 8388608
  float* Qb   = ws;
  float* Kb   = ws + QKV;
  float* Vb   = ws + 2 * QKV;
  float* Ob   = ws + 3 * QKV;
  float* cosT = ws + 4 * QKV;
  float* sinT = cosT + Sc * 64;
  // total = 4*QKV + 2*S*64 floats = ~135.3 MB

  rope_table_kernel<<<(Sc * 64) / 256, 256, 0, stream>>>(cosT, sinT);

  dim3 g1(N3 / 128, Mc / 128);   // 48 x 32
  sgemm128<0><<<g1, 256, 0, stream>>>(x, Wqkv, bqkv, Qb, Kb, Vb, N3);

  rope_kernel<<<Bc * Hc * Sc, 128, 0, stream>>>(Qb, Kb, cosT, sinT);

  attn_kernel<<<Bc * Hc * (Sc / 32), 256, 0, stream>>>(Qb, Kb, Vb, Ob);

  dim3 g2(Dc / 128, Mc / 128);   // 16 x 32
  sgemm128<1><<<g2, 256, 0, stream>>>(Ob, Wo, bo, out, nullptr, nullptr, Dc);
}

// Round 3
// 493.386 us; speedup vs baseline: 6.7011x; 6.7011x over previous
//
#include <hip/hip_runtime.h>
#include <math.h>

// Problem constants (B,S,D,H fixed by the reference)
constexpr int Bc = 2, Sc = 2048, Dc = 2048, Hc = 16, DHc = 128;
constexpr int Mc = Bc * Sc;   // 4096 rows of x
constexpr int N3 = 3 * Dc;    // 6144

typedef short     s16x8  __attribute__((ext_vector_type(8)));
typedef float     f32x4  __attribute__((ext_vector_type(4)));
typedef unsigned short ushortv8 __attribute__((ext_vector_type(8)));

__device__ __forceinline__ unsigned short f2bf(float f) {
  unsigned u = __float_as_uint(f);
  u += 0x7fffu + ((u >> 16) & 1u);       // RNE
  return (unsigned short)(u >> 16);
}
__device__ __forceinline__ float bf2f(unsigned short h) {
  return __uint_as_float(((unsigned)h) << 16);
}

// Async global->LDS, 16B per lane. LDS base must be wave-uniform; hardware
// writes base + lane*16. Global address is per-lane. [m97/m104 semantics]
__device__ __forceinline__ void gld_lds16(const unsigned short* g, unsigned short* l) {
  __builtin_amdgcn_global_load_lds(
      (const __attribute__((address_space(1))) void*)g,
      (__attribute__((address_space(3))) void*)l, 16, 0, 0);
}

// DPP helpers: reduction across 16-lane rows without touching the LDS pipe.
template<int CTRL>
__device__ __forceinline__ float dppf(float x) {
  return __int_as_float(
      __builtin_amdgcn_update_dpp(0, __float_as_int(x), CTRL, 0xF, 0xF, true));
}
__device__ __forceinline__ float rowmax16(float v) {
  v = fmaxf(v, dppf<0xB1>(v));    // xor1: quad_perm(1,0,3,2)
  v = fmaxf(v, dppf<0x4E>(v));    // xor2: quad_perm(2,3,0,1)
  v = fmaxf(v, dppf<0x141>(v));   // xor4: row_half_mirror
  v = fmaxf(v, dppf<0x140>(v));   // xor8: row_mirror
  return v;
}
__device__ __forceinline__ float rowsum16(float v) {
  v += dppf<0xB1>(v);
  v += dppf<0x4E>(v);
  v += dppf<0x141>(v);
  v += dppf<0x140>(v);
  return v;
}

// ---------------------------------------------------------------------------
// RoPE cos/sin tables: [S][64] each.
// ---------------------------------------------------------------------------
__global__ void rope_table_kernel(float* __restrict__ cosT, float* __restrict__ sinT) {
  int idx = blockIdx.x * 256 + threadIdx.x;   // S*64 = 131072 total
  int s = idx >> 6, j = idx & 63;
  float inv = powf(10000.0f, -(float)(2 * j) / 128.0f);
  float a = (float)s * inv;
  cosT[idx] = cosf(a);
  sinT[idx] = sinf(a);
}

// ---------------------------------------------------------------------------
// fp32 -> bf16 elementwise (x). 8 elements/thread.
// ---------------------------------------------------------------------------
__global__ void cvt_bf16(const float* __restrict__ in, unsigned short* __restrict__ outp) {
  size_t i = ((size_t)blockIdx.x * 256 + threadIdx.x) * 8;
  float4 a = *(const float4*)&in[i];
  float4 b = *(const float4*)&in[i + 4];
  ushortv8 o;
  o[0] = f2bf(a.x); o[1] = f2bf(a.y); o[2] = f2bf(a.z); o[3] = f2bf(a.w);
  o[4] = f2bf(b.x); o[5] = f2bf(b.y); o[6] = f2bf(b.z); o[7] = f2bf(b.w);
  *(ushortv8*)&outp[i] = o;
}

// ---------------------------------------------------------------------------
// fp32 [R][C] -> bf16 [C][R] transpose-convert via 64x64 LDS tile.
// Pad 69: write banks 2-way aliased only, read rcol-stride 40%32=8 -> 2-way.
// ---------------------------------------------------------------------------
__global__ __launch_bounds__(256)
void cvt_transpose(const float* __restrict__ in, unsigned short* __restrict__ outp,
                   int R, int C) {
  __shared__ float Ls[64][69];
  const int nTc = C >> 6;
  const int tc = blockIdx.x % nTc, tr = blockIdx.x / nTc;
  const int r0 = tr << 6, c0 = tc << 6;
#pragma unroll
  for (int i = 0; i < 4; ++i) {
    int id = threadIdx.x + 256 * i;        // 0..1023
    int row = id >> 4, col = (id & 15) << 2;
    float4 v = *(const float4*)&in[(size_t)(r0 + row) * C + c0 + col];
    Ls[row][col] = v.x; Ls[row][col + 1] = v.y;
    Ls[row][col + 2] = v.z; Ls[row][col + 3] = v.w;
  }
  __syncthreads();
#pragma unroll
  for (int i = 0; i < 2; ++i) {
    int id = threadIdx.x + 256 * i;        // 0..511
    int crow = id >> 3, rcol = (id & 7) << 3;
    ushortv8 o;
#pragma unroll
    for (int jj = 0; jj < 8; ++jj) o[jj] = f2bf(Ls[rcol + jj][crow]);
    *(ushortv8*)&outp[(size_t)(c0 + crow) * R + r0 + rcol] = o;
  }
}

// ---------------------------------------------------------------------------
// bf16 MFMA GEMM, C[M,N] = A[M,2048] @ Bt[N,2048]^T + bias.
// m97 structure: 128x128 tile, BK=32, 4 waves (2x2), 4x4 frags/wave,
// global_load_lds width-16 staging, 2 barriers per K-step.
// EPI=0: +bias, ->bf16, scatter into Q/K/V [B*H,S,DH].
// EPI=1: +bias, fp32 row-major store.
// ---------------------------------------------------------------------------
template<int EPI>
__global__ __launch_bounds__(256)
void gemm_bt(const unsigned short* __restrict__ A, const unsigned short* __restrict__ Bt,
             const float* __restrict__ bias, unsigned short* __restrict__ Qo,
             unsigned short* __restrict__ Ko, unsigned short* __restrict__ Vo,
             float* __restrict__ outF, int Ndim)
{
  constexpr int Kd = 2048;
  __shared__ unsigned short As[128 * 32];
  __shared__ unsigned short Bs[128 * 32];
  const int t = threadIdx.x;
  const int w = t >> 6, l = t & 63;
  const int l15 = l & 15, g = l >> 4;
  const int wr = w >> 1, wc = w & 1;
  const int m0 = blockIdx.y * 128, n0 = blockIdx.x * 128;
  const int srow = l >> 2;           // staging: row within 16-row group
  const int scol = (l & 3) * 8;      // staging: k-element offset (16B)

  f32x4 acc[4][4];
#pragma unroll
  for (int mi = 0; mi < 4; ++mi)
#pragma unroll
    for (int ni = 0; ni < 4; ++ni) acc[mi][ni] = (f32x4){0.f, 0.f, 0.f, 0.f};

  for (int k0 = 0; k0 < Kd; k0 += 32) {
    __syncthreads();                 // previous iter's LDS reads drained
#pragma unroll
    for (int j = 0; j < 2; ++j) {
      int rowg = (w * 2 + j) * 16 + srow;
      gld_lds16(&A[(size_t)(m0 + rowg) * Kd + k0 + scol], &As[(w * 2 + j) * 512]);
      gld_lds16(&Bt[(size_t)(n0 + rowg) * Kd + k0 + scol], &Bs[(w * 2 + j) * 512]);
    }
    __syncthreads();                 // vmcnt(0) drain -> LDS tile ready

    s16x8 af[4], bf[4];
#pragma unroll
    for (int mi = 0; mi < 4; ++mi)
      af[mi] = *(const s16x8*)&As[(wr * 64 + mi * 16 + l15) * 32 + g * 8];
#pragma unroll
    for (int ni = 0; ni < 4; ++ni)
      bf[ni] = *(const s16x8*)&Bs[(wc * 64 + ni * 16 + l15) * 32 + g * 8];
#pragma unroll
    for (int mi = 0; mi < 4; ++mi)
#pragma unroll
      for (int ni = 0; ni < 4; ++ni)
        acc[mi][ni] = __builtin_amdgcn_mfma_f32_16x16x32_bf16(af[mi], bf[ni], acc[mi][ni], 0, 0, 0);
  }

  if (EPI == 0) {
    // 128-col tile lies inside one part (q/k/v) and one head (both 128-aligned)
    const int part = n0 >> 11;
    const int h = (n0 >> 7) & 15;
    unsigned short* outp = (part == 0) ? Qo : (part == 1 ? Ko : Vo);
#pragma unroll
    for (int mi = 0; mi < 4; ++mi) {
#pragma unroll
      for (int r = 0; r < 4; ++r) {
        int row = m0 + wr * 64 + mi * 16 + g * 4 + r;
        int b_ = row >> 11, s_ = row & 2047;
        unsigned short* dst = outp + (((size_t)(b_ * Hc + h) * Sc + s_) << 7);
#pragma unroll
        for (int ni = 0; ni < 4; ++ni) {
          int col = wc * 64 + ni * 16 + l15;
          dst[col] = f2bf(acc[mi][ni][r] + bias[n0 + col]);
        }
      }
    }
  } else {
#pragma unroll
    for (int mi = 0; mi < 4; ++mi) {
#pragma unroll
      for (int r = 0; r < 4; ++r) {
        int row = m0 + wr * 64 + mi * 16 + g * 4 + r;
#pragma unroll
        for (int ni = 0; ni < 4; ++ni) {
          int col = wc * 64 + ni * 16 + l15;
          outF[(size_t)row * Ndim + n0 + col] = acc[mi][ni][r] + bias[n0 + col];
        }
      }
    }
  }
}

// ---------------------------------------------------------------------------
// In-place RoPE on bf16 Q,K ([B*H, S, 128]). Block = one s-row of Q AND K.
// Q additionally pre-scaled by 1/sqrt(DH) (distributes into QK^T scores).
// ---------------------------------------------------------------------------
__global__ void rope_bf16(unsigned short* __restrict__ Q, unsigned short* __restrict__ K,
                          const float* __restrict__ cosT, const float* __restrict__ sinT) {
  const int row = blockIdx.x;        // 0 .. B*H*S-1
  const int t = threadIdx.x;
  const int half = t >> 7, j = t & 127;
  const int s = row & (Sc - 1);
  __shared__ float sh[2][128];
  unsigned short* buf = half ? K : Q;
  const size_t off = (size_t)row * DHc + j;
  float val = bf2f(buf[off]);
  sh[half][j] = val;
  __syncthreads();
  const float c  = cosT[s * 64 + (j & 63)];
  const float sn = sinT[s * 64 + (j & 63)];
  float rot = (j < 64) ? sh[half][2 * j + 1] : -sh[half][2 * (j - 64)];
  float r = val * c + rot * sn;
  if (!half) r *= 0.08838834764831845f;   // 1/sqrt(128) folded into Q
  buf[off] = f2bf(r);
}

// ---------------------------------------------------------------------------
// V transpose: Vbf [bh][S][128] -> Vtb [bh][128][S] (bf16).
// ---------------------------------------------------------------------------
__global__ __launch_bounds__(256)
void vtrans(const unsigned short* __restrict__ V, unsigned short* __restrict__ Vt)
{
  __shared__ __align__(16) unsigned short Ls[64][132];
  const int bid = blockIdx.x;          // bh*32 + st
  const int st = bid & 31, bh = bid >> 5;
  const int s0 = st * 64;
  const unsigned short* src = V + ((size_t)bh * Sc + s0) * DHc;
  unsigned short* dst = Vt + (size_t)bh * DHc * Sc + s0;
#pragma unroll
  for (int r = 0; r < 4; ++r) {
    int id = threadIdx.x + 256 * r;          // 0..1023
    int row = id >> 4, col = (id & 15) * 8;
    *(ushortv8*)&Ls[row][col] = *(const ushortv8*)&src[(size_t)row * DHc + col];
  }
  __syncthreads();
#pragma unroll
  for (int r = 0; r < 4; ++r) {
    int id = threadIdx.x + 256 * r;
    int d = id >> 3, scol = (id & 7) * 8;
    ushortv8 o;
#pragma unroll
    for (int jj = 0; jj < 8; ++jj) o[jj] = Ls[scol + jj][d];
    *(ushortv8*)&dst[(size_t)d * Sc + scol] = o;
  }
}

// ---------------------------------------------------------------------------
// bf16 MFMA flash attention (round-1 structure, bf16 output).
// 4 waves; 128 q-rows/block (32/wave, 2 m-tiles). 64-key tiles.
// ---------------------------------------------------------------------------
__global__ __launch_bounds__(256)
void attn_mfma(const unsigned short* __restrict__ Qg, const unsigned short* __restrict__ Kg,
               const unsigned short* __restrict__ Vtg, unsigned short* __restrict__ Og)
{
  __shared__ __align__(16) unsigned short Ks[64][136];
  __shared__ __align__(16) unsigned short Vs[128][72];
  __shared__ __align__(16) unsigned short Ps[4][32][72];
  const int t = threadIdx.x;
  const int w = t >> 6, l = t & 63;
  const int l15 = l & 15, g = l >> 4;
  const int bid = blockIdx.x;
  const int qt = bid & 15, bh = bid >> 4;   // 16 q-tiles, 32 bh
  const int q0 = qt * 128;
  const size_t kbase = (size_t)bh * Sc * DHc;   // Q,K layout [bh][S][128]
  const size_t vbase = (size_t)bh * DHc * Sc;   // Vt layout [bh][128][S]

  s16x8 qf[2][4];
#pragma unroll
  for (int mi = 0; mi < 2; ++mi)
#pragma unroll
    for (int ks = 0; ks < 4; ++ks)
      qf[mi][ks] = *(const s16x8*)&Qg[kbase + (size_t)(q0 + w * 32 + mi * 16 + l15) * DHc
                                      + ks * 32 + 8 * g];

  f32x4 acc[2][8];
#pragma unroll
  for (int mi = 0; mi < 2; ++mi)
#pragma unroll
    for (int dt = 0; dt < 8; ++dt) acc[mi][dt] = (f32x4){0.f, 0.f, 0.f, 0.f};
  float m_i[2][4], l_i[2][4];
#pragma unroll
  for (int mi = 0; mi < 2; ++mi)
#pragma unroll
    for (int r = 0; r < 4; ++r) { m_i[mi][r] = -1.0e30f; l_i[mi][r] = 0.f; }

  for (int kt0 = 0; kt0 < Sc; kt0 += 64) {
    __syncthreads();   // previous tile's LDS reads done
#pragma unroll
    for (int r = 0; r < 4; ++r) {
      int id = t + 256 * r;
      int row = id >> 4, col = (id & 15) * 8;
      *(ushortv8*)&Ks[row][col] =
          *(const ushortv8*)&Kg[kbase + (size_t)(kt0 + row) * DHc + col];
    }
#pragma unroll
    for (int r = 0; r < 4; ++r) {
      int id = t + 256 * r;
      int row = id >> 3, col = (id & 7) * 8;
      *(ushortv8*)&Vs[row][col] =
          *(const ushortv8*)&Vtg[vbase + (size_t)row * Sc + kt0 + col];
    }
    __syncthreads();

    // ---- S = Q K^T (pre-scaled)
    f32x4 sv[2][4];
#pragma unroll
    for (int mi = 0; mi < 2; ++mi)
#pragma unroll
      for (int nt = 0; nt < 4; ++nt) sv[mi][nt] = (f32x4){0.f, 0.f, 0.f, 0.f};
#pragma unroll
    for (int nt = 0; nt < 4; ++nt) {
#pragma unroll
      for (int ks = 0; ks < 4; ++ks) {
        s16x8 bf = *(const s16x8*)&Ks[nt * 16 + l15][ks * 32 + 8 * g];
        sv[0][nt] = __builtin_amdgcn_mfma_f32_16x16x32_bf16(qf[0][ks], bf, sv[0][nt], 0, 0, 0);
        sv[1][nt] = __builtin_amdgcn_mfma_f32_16x16x32_bf16(qf[1][ks], bf, sv[1][nt], 0, 0, 0);
      }
    }

    // ---- online softmax; rows = mi*16 + g*4 + r, cols = nt*16 + l15
#pragma unroll
    for (int mi = 0; mi < 2; ++mi) {
#pragma unroll
      for (int r = 0; r < 4; ++r) {
        float vmax = fmaxf(fmaxf(sv[mi][0][r], sv[mi][1][r]),
                           fmaxf(sv[mi][2][r], sv[mi][3][r]));
        vmax = rowmax16(vmax);
        float mnew = fmaxf(m_i[mi][r], vmax);
        float scf = __expf(m_i[mi][r] - mnew);
        float rs = 0.f;
#pragma unroll
        for (int nt = 0; nt < 4; ++nt) {
          float p = __expf(sv[mi][nt][r] - mnew);
          rs += p;
          Ps[w][mi * 16 + g * 4 + r][nt * 16 + l15] = f2bf(p);
        }
        rs = rowsum16(rs);
        l_i[mi][r] = l_i[mi][r] * scf + rs;
        m_i[mi][r] = mnew;
#pragma unroll
        for (int dt = 0; dt < 8; ++dt) acc[mi][dt][r] *= scf;
      }
    }

    // ---- P fragments (same-wave LDS round trip; in-order LDS pipe)
    s16x8 pf[2][2];
#pragma unroll
    for (int mi = 0; mi < 2; ++mi)
#pragma unroll
      for (int ks = 0; ks < 2; ++ks)
        pf[mi][ks] = *(const s16x8*)&Ps[w][mi * 16 + l15][ks * 32 + 8 * g];

    // ---- O += P V
#pragma unroll
    for (int dt = 0; dt < 8; ++dt) {
#pragma unroll
      for (int ks = 0; ks < 2; ++ks) {
        s16x8 vf = *(const s16x8*)&Vs[dt * 16 + l15][ks * 32 + 8 * g];
        acc[0][dt] = __builtin_amdgcn_mfma_f32_16x16x32_bf16(pf[0][ks], vf, acc[0][dt], 0, 0, 0);
        acc[1][dt] = __builtin_amdgcn_mfma_f32_16x16x32_bf16(pf[1][ks], vf, acc[1][dt], 0, 0, 0);
      }
    }
  }

  // ---- epilogue: divide by l, store bf16 to [B,S,D]
  const int b = bh >> 4, h = bh & 15;
#pragma unroll
  for (int mi = 0; mi < 2; ++mi) {
#pragma unroll
    for (int r = 0; r < 4; ++r) {
      float inv = 1.0f / l_i[mi][r];
      int srow = q0 + w * 32 + mi * 16 + g * 4 + r;
      unsigned short* dst = Og + ((size_t)(b * Sc + srow)) * Dc + h * DHc;
#pragma unroll
      for (int dt = 0; dt < 8; ++dt)
        dst[dt * 16 + l15] = f2bf(acc[mi][dt][r] * inv);
    }
  }
}

// ---------------------------------------------------------------------------
extern "C" void kernel_launch(void* const* d_in, const int* in_sizes, int n_in,
                              void* d_out, int out_size, void* d_ws, size_t ws_size,
                              hipStream_t stream) {
  const float* x    = (const float*)d_in[0];
  const float* Wqkv = (const float*)d_in[1];
  const float* bqkv = (const float*)d_in[2];
  const float* Wo   = (const float*)d_in[3];
  const float* bo   = (const float*)d_in[4];
  float* out = (float*)d_out;
  char* p = (char*)d_ws;

  // Workspace: exactly 135,266,304 B (== round-0 proven footprint)
  unsigned short* Ob  = (unsigned short*)p;  p += 16777216;   // attn out bf16 [B,S,D]
  float* cosT         = (float*)p;           p += 524288;
  float* sinT         = (float*)p;           p += 524288;
  unsigned short* xbf = (unsigned short*)p;  p += 16777216;   // x bf16 [4096][2048]
  unsigned short* Wqt = (unsigned short*)p;  p += 25165824;   // Wqkv^T bf16 [6144][2048]
  unsigned short* Wot = (unsigned short*)p;  p += 8388608;    // Wo^T bf16 [2048][2048]
  unsigned short* Qbf = (unsigned short*)p;  p += 16777216;
  unsigned short* Kbf = (unsigned short*)p;  p += 16777216;
  unsigned short* Vbf = (unsigned short*)p;  p += 16777216;
  unsigned short* Vtb = (unsigned short*)p;  p += 16777216;

  rope_table_kernel<<<(Sc * 64) / 256, 256, 0, stream>>>(cosT, sinT);

  cvt_bf16<<<(Mc * Dc) / (256 * 8), 256, 0, stream>>>(x, xbf);
  cvt_transpose<<<(N3 / 64) * (Dc / 64), 256, 0, stream>>>(Wqkv, Wqt, Dc, N3);
  cvt_transpose<<<(Dc / 64) * (Dc / 64), 256, 0, stream>>>(Wo, Wot, Dc, Dc);

  dim3 g1(N3 / 128, Mc / 128);   // 48 x 32
  gemm_bt<0><<<g1, 256, 0, stream>>>(xbf, Wqt, bqkv, Qbf, Kbf, Vbf, nullptr, N3);

  rope_bf16<<<Bc * Hc * Sc, 256, 0, stream>>>(Qbf, Kbf, cosT, sinT);

  vtrans<<<Bc * Hc * (Sc / 64), 256, 0, stream>>>(Vbf, Vtb);

  attn_mfma<<<Bc * Hc * (Sc / 128), 256, 0, stream>>>(Qbf, Kbf, Vtb, Ob);

  dim3 g2(Dc / 128, Mc / 128);   // 16 x 32
  gemm_bt<1><<<g2, 256, 0, stream>>>(Ob, Wot, bo, nullptr, nullptr, nullptr, out, Dc);
}